// Round 17
// baseline (240.889 us; speedup 1.0000x reference)
//
#include <hip/hip_runtime.h>
#include <math.h>

// Bahdanau attention: B=32, T=2048, D=512, Q=512, fp32.
// out = [score (B*T), weights (B*T), expectation (B*D)] concatenated.
// Masked positions: finite sentinel -1e30 (ref has -inf; |inf diff| <= inf thr,
// exp underflows to 0 identically).
//
// R17 = R16 with the fragment-layout lane order changed from (hi4*16+lo16)
// to (lo16*4+hi4). The GEMM reads frags as base+perm(lane)*16B -- any
// permutation of the 1KB block is equally coalesced -- but the new order
// makes the CONVERTERS read 128B-contiguous per 4 lanes (was 32B scattered
// across rows 2KB apart; convX ran at ~3.3 TB/s, 80us of the 206us total).

#define TPB 256
constexpr int B = 32, T = 2048, D = 512, Qd = 512;
constexpr int NROW = B * T;
#define NEG_SENTINEL (-1e30f)

typedef __attribute__((ext_vector_type(8))) short bf16x8;
typedef __attribute__((ext_vector_type(4))) float f32x4;

// LDS-only barrier: ds ops drained, vmem stays in flight.
__device__ __forceinline__ void lds_barrier() {
    asm volatile("s_waitcnt lgkmcnt(0)" ::: "memory");
    __builtin_amdgcn_s_barrier();
}

// HW packed fp32->bf16 RNE: result.lo16 = bf16(a), result.hi16 = bf16(b)
__device__ __forceinline__ unsigned cvtpk(float a, float b) {
    unsigned r;
    asm("v_cvt_pk_bf16_f32 %0, %1, %2" : "=v"(r) : "v"(a), "v"(b));
    return r;
}
// split two floats into packed-hi (return) and packed-lo bf16 pairs
__device__ __forceinline__ unsigned packsplit(float f0, float f1, unsigned& lopack) {
    unsigned hp = cvtpk(f0, f1);
    float h0 = __builtin_bit_cast(float, hp << 16);
    float h1 = __builtin_bit_cast(float, hp & 0xFFFF0000u);
    lopack = cvtpk(f0 - h0, f1 - h1);
    return hp;
}
__device__ __forceinline__ void cvt8(const float4 a, const float4 b, uint4& hi, uint4& lo) {
    hi.x = packsplit(a.x, a.y, lo.x);
    hi.y = packsplit(a.z, a.w, lo.y);
    hi.z = packsplit(b.x, b.y, lo.z);
    hi.w = packsplit(b.z, b.w, lo.w);
}
// fast tanh: saturating exp form, |err| ~ 1e-7
__device__ __forceinline__ float fast_tanh(float x) {
    float a = fabsf(x);
    float e = __expf(-2.f * a);
    float t = (1.f - e) / (1.f + e);
    return copysignf(t, x);
}

// ---------------------------------------------------------------- K1: uq[b][e]
__global__ void k_uq(const float* __restrict__ query, const float* __restrict__ u,
                     float* __restrict__ uq) {
    int b = blockIdx.x;
    __shared__ float q_s[Qd];
    for (int i = threadIdx.x; i < Qd; i += TPB) q_s[i] = query[b * Qd + i];
    __syncthreads();
    for (int e = threadIdx.x; e < D; e += TPB) {
        const float4* urow = (const float4*)(u + (size_t)e * Qd);
        float acc = 0.f;
        for (int q4 = 0; q4 < Qd / 4; ++q4) {
            float4 uu = urow[q4];
            float4 qq = *(const float4*)(q_s + q4 * 4);
            acc += uu.x * qq.x + uu.y * qq.y + uu.z * qq.z + uu.w * qq.w;
        }
        uq[b * D + e] = acc;
    }
}

// ---------------------------------------------------------------- K2: W -> split-bf16 fragment layout
// Storage: g = ((nt*16 + kc)*8 + cb)*64 + lo16*4 + hi4
//   e = nt*128 + cb*16 + lo16, d0 = kc*32 + hi4*8
// Consecutive threads: hi4 fastest -> 4 lanes read 128B contiguous of one
// W row; writes WhF[g] perfectly coalesced.
__global__ void k_convW(const float* __restrict__ W,
                        uint4* __restrict__ WhF, uint4* __restrict__ WlF) {
    const int g = blockIdx.x * 256 + threadIdx.x;   // 0..32767
    const int hi4 = g & 3, lo16 = (g >> 2) & 15, cb = (g >> 6) & 7;
    const int kc = (g >> 9) & 15, nt = g >> 13;
    const int e = nt * 128 + cb * 16 + lo16;
    const float4* src = (const float4*)(W + (size_t)e * D + kc * 32 + hi4 * 8);
    float4 a = src[0], bq = src[1];
    uint4 hi, lo;
    cvt8(a, bq, hi, lo);
    WhF[g] = hi;
    WlF[g] = lo;
}

// ---------------------------------------------------------------- K2b: X -> split-bf16 fragment layout
// Storage: g = ((mt*16 + kc)*8 + rb)*64 + lo16*4 + hi4
//   row = mt*128 + rb*16 + lo16, d0 = kc*32 + hi4*8
__global__ void k_convX(const float* __restrict__ X,
                        uint4* __restrict__ XhF, uint4* __restrict__ XlF) {
    const int g = blockIdx.x * 256 + threadIdx.x;   // 0..NROW*64-1
    const int hi4 = g & 3, lo16 = (g >> 2) & 15, rb = (g >> 6) & 7;
    const int kc = (g >> 9) & 15, mt = g >> 13;
    const int row = mt * 128 + rb * 16 + lo16;
    const float4* src = (const float4*)(X + (size_t)row * D + kc * 32 + hi4 * 8);
    float4 a = src[0], bq = src[1];
    uint4 hi, lo;
    cvt8(a, bq, hi, lo);
    XhF[g] = hi;
    XlF[g] = lo;
}

// ---------------------------------------------------------------- K3a: STREAMING split-bf16 MFMA GEMM (fast path)
// Block 128x128, 4 waves (2m x 2n), wave 64x64 = 4x4 frags of 16x16x32.
// Both operands preconverted frag-layout: global->reg, coalesced (lperm is a
// permutation within each 1KB frag block), no LDS, no barriers in the K-loop.
// 1-step register double-buffer. 3 MFMA products in fp32 acc.
__global__ __launch_bounds__(256, 2) void k_gemm_stream(
    const uint4* __restrict__ XhF, const uint4* __restrict__ XlF,
    const uint4* __restrict__ WhF, const uint4* __restrict__ WlF,
    const float* __restrict__ v,
    const float* __restrict__ uqg,
    float* __restrict__ partialS)   // [4][NROW]
{
    __shared__ float scr[2][128];

    // XCD-bijective swizzle (2048 % 8 == 0)
    const int gidx = blockIdx.x;
    const int logical = (gidx & 7) * 256 + (gidx >> 3);
    const int mt = logical >> 2, nt = logical & 3;
    const int row0 = mt * 128, e0 = nt * 128;
    const int b = row0 >> 11;

    const int tid = threadIdx.x, lane = tid & 63, wid = tid >> 6;
    const int wm = wid >> 1, wn = wid & 1;
    const int lo16 = lane & 15, hi4 = lane >> 4;
    const int lperm = lo16 * 4 + hi4;   // storage position of this lane's frag element

    const uint4* XhB = XhF + ((size_t)mt * 16) * 8 * 64 + (wm * 4) * 64 + lperm;
    const uint4* XlB = XlF + ((size_t)mt * 16) * 8 * 64 + (wm * 4) * 64 + lperm;
    const uint4* WhB = WhF + ((size_t)nt * 16) * 8 * 64 + (wn * 4) * 64 + lperm;
    const uint4* WlB = WlF + ((size_t)nt * 16) * 8 * 64 + (wn * 4) * 64 + lperm;

    f32x4 acc[4][4];
#pragma unroll
    for (int i = 0; i < 4; ++i)
#pragma unroll
        for (int j = 0; j < 4; ++j) acc[i][j] = (f32x4){0.f, 0.f, 0.f, 0.f};

    uint4 ah[2][4], al[2][4], bh[2][4], bl[2][4];
    // prologue: step 0 frags
#pragma unroll
    for (int f = 0; f < 4; ++f) {
        ah[0][f] = XhB[f * 64];
        al[0][f] = XlB[f * 64];
        bh[0][f] = WhB[f * 64];
        bl[0][f] = WlB[f * 64];
    }

#pragma unroll
    for (int kc = 0; kc < 16; ++kc) {
        const int cur = kc & 1, nxt = cur ^ 1;
        // issue next-step loads first (16 loads in flight across the MFMAs)
        if (kc + 1 < 16) {
            const size_t off = (size_t)(kc + 1) * 512;
#pragma unroll
            for (int f = 0; f < 4; ++f) {
                ah[nxt][f] = XhB[off + f * 64];
                al[nxt][f] = XlB[off + f * 64];
                bh[nxt][f] = WhB[off + f * 64];
                bl[nxt][f] = WlB[off + f * 64];
            }
        }
        // 48 MFMA on current frags (compiler waits vmcnt(16) for cur only)
#pragma unroll
        for (int fc = 0; fc < 4; ++fc) {
            const bf16x8 bH = __builtin_bit_cast(bf16x8, bh[cur][fc]);
            const bf16x8 bL = __builtin_bit_cast(bf16x8, bl[cur][fc]);
#pragma unroll
            for (int fr = 0; fr < 4; ++fr) {
                const bf16x8 aH = __builtin_bit_cast(bf16x8, ah[cur][fr]);
                const bf16x8 aL = __builtin_bit_cast(bf16x8, al[cur][fr]);
                acc[fr][fc] = __builtin_amdgcn_mfma_f32_16x16x32_bf16(aH, bH, acc[fr][fc], 0, 0, 0);
                acc[fr][fc] = __builtin_amdgcn_mfma_f32_16x16x32_bf16(aH, bL, acc[fr][fc], 0, 0, 0);
                acc[fr][fc] = __builtin_amdgcn_mfma_f32_16x16x32_bf16(aL, bH, acc[fr][fc], 0, 0, 0);
            }
        }
    }

    // ---- epilogue: p[row] = sum_col tanh(acc + uq[col]) * v[col]
    const int colbase = e0 + wn * 64;
#pragma unroll
    for (int fr = 0; fr < 4; ++fr) {
        float ps[4] = {0.f, 0.f, 0.f, 0.f};
#pragma unroll
        for (int fc = 0; fc < 4; ++fc) {
            const int col = colbase + fc * 16 + lo16;
            const float uqc = uqg[b * D + col];
            const float vc  = v[col];
#pragma unroll
            for (int i = 0; i < 4; ++i)
                ps[i] += fast_tanh(acc[fr][fc][i] + uqc) * vc;
        }
#pragma unroll
        for (int i = 0; i < 4; ++i) {
            float p = ps[i];
#pragma unroll
            for (int off = 8; off >= 1; off >>= 1) p += __shfl_xor(p, off, 16);
            if (lo16 == 0) scr[wn][wm * 64 + fr * 16 + hi4 * 4 + i] = p;
        }
    }
    __syncthreads();
    if (tid < 128)
        partialS[(size_t)nt * NROW + row0 + tid] = scr[0][tid] + scr[1][tid];
}

// ---------------------------------------------------------------- K3b: fallback GEMM (R13 structure; B reads use lperm layout)
__global__ __launch_bounds__(256, 4) void k_gemm(
    const float* __restrict__ X,
    const uint4* __restrict__ WhF,
    const uint4* __restrict__ WlF,
    const float* __restrict__ v,
    const float* __restrict__ uqg,
    float* __restrict__ partialS)   // [4][NROW]
{
    __shared__ uint4 Ah[2][4 * 128], Al[2][4 * 128];   // 32 KB
    __shared__ float scr[2][128];

    const int gidx = blockIdx.x;
    const int logical = (gidx & 7) * 256 + (gidx >> 3);
    const int mt = logical >> 2, nt = logical & 3;
    const int row0 = mt * 128, e0 = nt * 128;
    const int b = row0 >> 11;

    const int tid = threadIdx.x, lane = tid & 63, wid = tid >> 6;
    const int wm = wid >> 1, wn = wid & 1;
    const int lo16 = lane & 15, hi4 = lane >> 4;
    const int lperm = lo16 * 4 + hi4;
    const int arow = tid & 127, akh = tid >> 7;

    const float4* Xg = (const float4*)(X + (size_t)(row0 + arow) * D + akh * 16);
    const uint4* WhB = WhF + ((size_t)nt * 16) * 8 * 64 + (wn * 4) * 64 + lperm;
    const uint4* WlB = WlF + ((size_t)nt * 16) * 8 * 64 + (wn * 4) * 64 + lperm;

    f32x4 acc[4][4];
#pragma unroll
    for (int i = 0; i < 4; ++i)
#pragma unroll
        for (int j = 0; j < 4; ++j) acc[i][j] = (f32x4){0.f, 0.f, 0.f, 0.f};

    float4 xr[2][4];
#pragma unroll
    for (int i = 0; i < 4; ++i) xr[0][i] = Xg[i];
#pragma unroll
    for (int i = 0; i < 4; ++i) xr[1][i] = Xg[8 + i];
    {
        uint4 hp, lp;
        cvt8(xr[0][0], xr[0][1], hp, lp);
        Ah[0][(akh * 2 + 0) * 128 + arow] = hp;
        Al[0][(akh * 2 + 0) * 128 + arow] = lp;
        cvt8(xr[0][2], xr[0][3], hp, lp);
        Ah[0][(akh * 2 + 1) * 128 + arow] = hp;
        Al[0][(akh * 2 + 1) * 128 + arow] = lp;
    }

#pragma unroll
    for (int kc = 0; kc < 16; ++kc) {
        const int cur = kc & 1, nxt = cur ^ 1;
        lds_barrier();

        uint4 bhr[4], blr[4];
        {
            const uint4* wh = WhB + (size_t)kc * 8 * 64;
            const uint4* wl = WlB + (size_t)kc * 8 * 64;
#pragma unroll
            for (int fc = 0; fc < 4; ++fc) {
                bhr[fc] = wh[fc * 64];
                blr[fc] = wl[fc * 64];
            }
        }

        if (kc + 1 < 16) {
            uint4 hp, lp;
            cvt8(xr[nxt][0], xr[nxt][1], hp, lp);
            Ah[nxt][(akh * 2 + 0) * 128 + arow] = hp;
            Al[nxt][(akh * 2 + 0) * 128 + arow] = lp;
            cvt8(xr[nxt][2], xr[nxt][3], hp, lp);
            Ah[nxt][(akh * 2 + 1) * 128 + arow] = hp;
            Al[nxt][(akh * 2 + 1) * 128 + arow] = lp;
        }

        bf16x8 aH[4], aL[4];
#pragma unroll
        for (int fr = 0; fr < 4; ++fr) {
            const int idx = hi4 * 128 + wm * 64 + fr * 16 + lo16;
            aH[fr] = __builtin_bit_cast(bf16x8, Ah[cur][idx]);
            aL[fr] = __builtin_bit_cast(bf16x8, Al[cur][idx]);
        }

#pragma unroll
        for (int fc = 0; fc < 4; ++fc) {
            const bf16x8 bH = __builtin_bit_cast(bf16x8, bhr[fc]);
            const bf16x8 bL = __builtin_bit_cast(bf16x8, blr[fc]);
#pragma unroll
            for (int fr = 0; fr < 4; ++fr) {
                acc[fr][fc] = __builtin_amdgcn_mfma_f32_16x16x32_bf16(aH[fr], bH, acc[fr][fc], 0, 0, 0);
                acc[fr][fc] = __builtin_amdgcn_mfma_f32_16x16x32_bf16(aH[fr], bL, acc[fr][fc], 0, 0, 0);
                acc[fr][fc] = __builtin_amdgcn_mfma_f32_16x16x32_bf16(aL[fr], bH, acc[fr][fc], 0, 0, 0);
            }
        }

        if (kc + 2 < 16) {
#pragma unroll
            for (int i = 0; i < 4; ++i) xr[cur][i] = Xg[(kc + 2) * 8 + i];
        }
    }

    const int colbase = e0 + wn * 64;
#pragma unroll
    for (int fr = 0; fr < 4; ++fr) {
        float ps[4] = {0.f, 0.f, 0.f, 0.f};
#pragma unroll
        for (int fc = 0; fc < 4; ++fc) {
            const int col = colbase + fc * 16 + lo16;
            const float uqc = uqg[b * D + col];
            const float vc  = v[col];
#pragma unroll
            for (int i = 0; i < 4; ++i)
                ps[i] += fast_tanh(acc[fr][fc][i] + uqc) * vc;
        }
#pragma unroll
        for (int i = 0; i < 4; ++i) {
            float p = ps[i];
#pragma unroll
            for (int off = 8; off >= 1; off >>= 1) p += __shfl_xor(p, off, 16);
            if (lo16 == 0) scr[wn][wm * 64 + fr * 16 + hi4 * 4 + i] = p;
        }
    }
    __syncthreads();
    if (tid < 128)
        partialS[(size_t)nt * NROW + row0 + tid] = scr[0][tid] + scr[1][tid];
}

// ---------------------------------------------------------------- K4: combine 4 partials + mask
__global__ void k_combine(const float* __restrict__ partialS,
                          const int* __restrict__ lengths,
                          float* __restrict__ score) {
    const int i = blockIdx.x * TPB + threadIdx.x;
    const int b = i >> 11, t = i & (T - 1);
    float s = partialS[i] + partialS[NROW + i] + partialS[2 * NROW + i] + partialS[3 * NROW + i];
    score[i] = (t < lengths[b]) ? s : NEG_SENTINEL;
}

// ---------------------------------------------------------------- K5: softmax over t per batch
__global__ void k_softmax(const float* __restrict__ score, float* __restrict__ weights) {
    const int b = blockIdx.x;
    const float* s = score + (size_t)b * T;
    float m = -INFINITY;
    for (int t = threadIdx.x; t < T; t += TPB) m = fmaxf(m, s[t]);
#pragma unroll
    for (int off = 32; off >= 1; off >>= 1) m = fmaxf(m, __shfl_xor(m, off, 64));
    __shared__ float redm[4];
    if ((threadIdx.x & 63) == 0) redm[threadIdx.x >> 6] = m;
    __syncthreads();
    m = fmaxf(fmaxf(redm[0], redm[1]), fmaxf(redm[2], redm[3]));

    float sum = 0.f;
    for (int t = threadIdx.x; t < T; t += TPB) sum += __expf(s[t] - m);
#pragma unroll
    for (int off = 32; off >= 1; off >>= 1) sum += __shfl_xor(sum, off, 64);
    __shared__ float reds[4];
    if ((threadIdx.x & 63) == 0) reds[threadIdx.x >> 6] = sum;
    __syncthreads();
    const float inv = 1.f / (reds[0] + reds[1] + reds[2] + reds[3]);

    for (int t = threadIdx.x; t < T; t += TPB)
        weights[(size_t)b * T + t] = __expf(s[t] - m) * inv;
}

// ---------------------------------------------------------------- K6: partial expectation (16 chunks of 128 t)
__global__ void k_exp_partial(const float* __restrict__ X, const float* __restrict__ wts,
                              float* __restrict__ part) {
    const int b = blockIdx.x >> 4;
    const int c = blockIdx.x & 15;
    const int t0 = c * 128;
    const int d0 = threadIdx.x * 4;   // 128 threads x float4
    const float* Xb = X + ((size_t)b * T + t0) * D + d0;
    const float* wb = wts + (size_t)b * T + t0;
    float4 a = {0.f, 0.f, 0.f, 0.f};
    for (int t = 0; t < 128; ++t) {
        const float wgt = wb[t];
        const float4 x = *(const float4*)(Xb + (size_t)t * D);
        a.x += wgt * x.x; a.y += wgt * x.y; a.z += wgt * x.z; a.w += wgt * x.w;
    }
    *(float4*)(part + ((size_t)(b * 16 + c)) * D + d0) = a;
}

// ---------------------------------------------------------------- K7: reduce 16 partials
__global__ void k_exp_reduce(const float* __restrict__ part, float* __restrict__ out) {
    const int i = blockIdx.x * TPB + threadIdx.x;   // B*D
    const int b = i >> 9, d = i & 511;
    float a = 0.f;
#pragma unroll
    for (int c = 0; c < 16; ++c) a += part[((size_t)(b * 16 + c)) * D + d];
    out[i] = a;
}

// ----------------------------------------------------------------
extern "C" void kernel_launch(void* const* d_in, const int* in_sizes, int n_in,
                              void* d_out, int out_size, void* d_ws, size_t ws_size,
                              hipStream_t stream) {
    const float* X      = (const float*)d_in[0];
    const float* query  = (const float*)d_in[1];
    const int*   len    = (const int*)  d_in[2];
    const float* w      = (const float*)d_in[3];
    const float* u      = (const float*)d_in[4];
    const float* v      = (const float*)d_in[5];

    float* out     = (float*)d_out;
    float* score   = out;
    float* weights = out + (size_t)B * T;
    float* expec   = out + (size_t)2 * B * T;

    // ws layout (bytes):
    //   uq       : 65,536
    //   partialS : 1,048,576   (aliased later by 'part')
    //   WhF/WlF  : 524,288 x2
    //   XhF/XlF  : 67,108,864 x2   (fast path only)
    float* uq       = (float*)d_ws;
    float* partialS = uq + (size_t)B * D;
    uint4* WhF      = (uint4*)(partialS + (size_t)4 * NROW);
    uint4* WlF      = WhF + 32768;
    uint4* XhF      = WlF + 32768;
    uint4* XlF      = XhF + (size_t)NROW * 64;
    float* part     = partialS;

    const size_t WS_FAST = (size_t)65536 + 1048576 + 2 * 524288 + 2 * 67108864;
    const bool fast = ws_size >= WS_FAST;

    k_uq         <<<B,            TPB, 0, stream>>>(query, u, uq);
    k_convW      <<<128,          TPB, 0, stream>>>(w, WhF, WlF);
    if (fast) {
        k_convX      <<<NROW * 64 / TPB, TPB, 0, stream>>>(X, XhF, XlF);
        k_gemm_stream<<<2048,            TPB, 0, stream>>>(XhF, XlF, WhF, WlF, v, uq, partialS);
    } else {
        k_gemm       <<<2048,            TPB, 0, stream>>>(X, WhF, WlF, v, uq, partialS);
    }
    k_combine    <<<NROW / TPB,   TPB, 0, stream>>>(partialS, len, score);
    k_softmax    <<<B,            TPB, 0, stream>>>(score, weights);
    k_exp_partial<<<B * 16,       128, 0, stream>>>(X, weights, part);
    k_exp_reduce <<<B * D / TPB,  TPB, 0, stream>>>(part, expec);
}

// Round 18
// 206.991 us; speedup vs baseline: 1.1638x; 1.1638x over previous
//
#include <hip/hip_runtime.h>
#include <math.h>

// Bahdanau attention: B=32, T=2048, D=512, Q=512, fp32.
// out = [score (B*T), weights (B*T), expectation (B*D)] concatenated.
// Masked positions: finite sentinel -1e30 (ref has -inf; |inf diff| <= inf thr,
// exp underflows to 0 identically).
//
// R18: R16 layout reverted (identity lane order for ALL global frag reads --
// R17 proved the HW coalescer is lane-order-sensitive: a permuted read of the
// same 1KB block cost 45%). convX rewritten as an LDS transpose: global reads
// and writes both identity-coalesced; the permutation happens in LDS with an
// XOR swizzle (s ^ (row&7)) that is minimum-cycles on both sides.
// gemm_stream at launch_bounds(256,3): 140 unified regs fits 3 waves/SIMD.

#define TPB 256
constexpr int B = 32, T = 2048, D = 512, Qd = 512;
constexpr int NROW = B * T;
#define NEG_SENTINEL (-1e30f)

typedef __attribute__((ext_vector_type(8))) short bf16x8;
typedef __attribute__((ext_vector_type(4))) float f32x4;

// LDS-only barrier: ds ops drained, vmem stays in flight.
__device__ __forceinline__ void lds_barrier() {
    asm volatile("s_waitcnt lgkmcnt(0)" ::: "memory");
    __builtin_amdgcn_s_barrier();
}

// HW packed fp32->bf16 RNE: result.lo16 = bf16(a), result.hi16 = bf16(b)
__device__ __forceinline__ unsigned cvtpk(float a, float b) {
    unsigned r;
    asm("v_cvt_pk_bf16_f32 %0, %1, %2" : "=v"(r) : "v"(a), "v"(b));
    return r;
}
// split two floats into packed-hi (return) and packed-lo bf16 pairs
__device__ __forceinline__ unsigned packsplit(float f0, float f1, unsigned& lopack) {
    unsigned hp = cvtpk(f0, f1);
    float h0 = __builtin_bit_cast(float, hp << 16);
    float h1 = __builtin_bit_cast(float, hp & 0xFFFF0000u);
    lopack = cvtpk(f0 - h0, f1 - h1);
    return hp;
}
__device__ __forceinline__ void cvt8(const float4 a, const float4 b, uint4& hi, uint4& lo) {
    hi.x = packsplit(a.x, a.y, lo.x);
    hi.y = packsplit(a.z, a.w, lo.y);
    hi.z = packsplit(b.x, b.y, lo.z);
    hi.w = packsplit(b.z, b.w, lo.w);
}
// fast tanh: saturating exp form, |err| ~ 1e-7
__device__ __forceinline__ float fast_tanh(float x) {
    float a = fabsf(x);
    float e = __expf(-2.f * a);
    float t = (1.f - e) / (1.f + e);
    return copysignf(t, x);
}

// ---------------------------------------------------------------- K1: uq[b][e]
__global__ void k_uq(const float* __restrict__ query, const float* __restrict__ u,
                     float* __restrict__ uq) {
    int b = blockIdx.x;
    __shared__ float q_s[Qd];
    for (int i = threadIdx.x; i < Qd; i += TPB) q_s[i] = query[b * Qd + i];
    __syncthreads();
    for (int e = threadIdx.x; e < D; e += TPB) {
        const float4* urow = (const float4*)(u + (size_t)e * Qd);
        float acc = 0.f;
        for (int q4 = 0; q4 < Qd / 4; ++q4) {
            float4 uu = urow[q4];
            float4 qq = *(const float4*)(q_s + q4 * 4);
            acc += uu.x * qq.x + uu.y * qq.y + uu.z * qq.z + uu.w * qq.w;
        }
        uq[b * D + e] = acc;
    }
}

// ---------------------------------------------------------------- K2: W -> split-bf16 fragment layout (R16 order)
// idx16 = ((nt*16 + kc)*8 + cb)*64 + hi4*16 + lo16
//   e = nt*128 + cb*16 + lo16, d0 = kc*32 + hi4*8
// GEMM lane l reads position l (identity: l == (l>>4)*16 + (l&15)).
__global__ void k_convW(const float* __restrict__ W,
                        uint4* __restrict__ WhF, uint4* __restrict__ WlF) {
    const int g = blockIdx.x * 256 + threadIdx.x;   // 0..32767
    const int e = g >> 6, s = g & 63;               // d0 = s*8
    const float4* src = (const float4*)(W + (size_t)e * D + s * 8);
    float4 a = src[0], bq = src[1];
    uint4 hi, lo;
    cvt8(a, bq, hi, lo);
    const int nt = e >> 7, cb = (e >> 4) & 7, lo16 = e & 15;
    const int kc = s >> 2, hi4 = s & 3;
    const size_t idx = ((size_t)(nt * 16 + kc) * 8 + cb) * 64 + hi4 * 16 + lo16;
    WhF[idx] = hi;
    WlF[idx] = lo;
}

// ---------------------------------------------------------------- K2b: X -> frag layout via LDS transpose
// Block = 16 consecutive rows (one rb of one mt). Phase 1: coalesced row-major
// reads (wave covers contiguous 2KB), convert, LDS store at
// idx = row*64 + (s ^ (row&7))  [XOR swizzle -> min-cycle banks both phases].
// Phase 2: LDS read in frag order, write XhF/XlF identity-coalesced.
__global__ __launch_bounds__(256, 4) void k_convX(const float* __restrict__ X,
                        uint4* __restrict__ XhF, uint4* __restrict__ XlF) {
    __shared__ uint4 Lh[1024], Ll[1024];   // 16 KB + 16 KB
    const int blk = blockIdx.x;            // 4096 blocks x 16 rows
    const int mt = blk >> 3, rb = blk & 7;
    const size_t r0 = (size_t)blk * 16;
    const int tid = threadIdx.x;

#pragma unroll
    for (int pass = 0; pass < 4; ++pass) {
        const int flat8 = pass * 256 + tid;       // 0..1023
        const int row = flat8 >> 6, s = flat8 & 63;
        const float4* src = (const float4*)(X + (r0 + row) * D + s * 8);
        float4 a = src[0], bq = src[1];
        uint4 hi, lo;
        cvt8(a, bq, hi, lo);
        const int idx = row * 64 + (s ^ (row & 7));
        Lh[idx] = hi;
        Ll[idx] = lo;
    }
    __syncthreads();
    const size_t gbase = ((size_t)mt * 16 * 8) * 64 + (size_t)rb * 64;
#pragma unroll
    for (int pass = 0; pass < 4; ++pass) {
        const int kcg = pass * 4 + (tid >> 6);    // 0..15
        const int p = tid & 63;                   // hi4*16+lo16
        const int hi4 = p >> 4, lo16 = p & 15;
        const int sp = kcg * 4 + hi4;
        const int idx = lo16 * 64 + (sp ^ (lo16 & 7));
        const size_t g = gbase + (size_t)kcg * 8 * 64 + p;
        XhF[g] = Lh[idx];
        XlF[g] = Ll[idx];
    }
}

// ---------------------------------------------------------------- K3a: STREAMING split-bf16 MFMA GEMM (fast path)
// Block 128x128, 4 waves (2m x 2n), wave 64x64 = 4x4 frags of 16x16x32.
// Both operands preconverted frag-layout: global->reg at base+lane (identity,
// fully coalesced), no LDS, no barriers in the K-loop. 1-step register
// double-buffer. 3 MFMA products in fp32 acc. 3 blocks/CU.
__global__ __launch_bounds__(256, 3) void k_gemm_stream(
    const uint4* __restrict__ XhF, const uint4* __restrict__ XlF,
    const uint4* __restrict__ WhF, const uint4* __restrict__ WlF,
    const float* __restrict__ v,
    const float* __restrict__ uqg,
    float* __restrict__ partialS)   // [4][NROW]
{
    __shared__ float scr[2][128];

    // XCD-bijective swizzle (2048 % 8 == 0)
    const int gidx = blockIdx.x;
    const int logical = (gidx & 7) * 256 + (gidx >> 3);
    const int mt = logical >> 2, nt = logical & 3;
    const int row0 = mt * 128, e0 = nt * 128;
    const int b = row0 >> 11;

    const int tid = threadIdx.x, lane = tid & 63, wid = tid >> 6;
    const int wm = wid >> 1, wn = wid & 1;
    const int lo16 = lane & 15, hi4 = lane >> 4;

    const uint4* XhB = XhF + ((size_t)mt * 16) * 8 * 64 + (wm * 4) * 64 + lane;
    const uint4* XlB = XlF + ((size_t)mt * 16) * 8 * 64 + (wm * 4) * 64 + lane;
    const uint4* WhB = WhF + ((size_t)nt * 16) * 8 * 64 + (wn * 4) * 64 + lane;
    const uint4* WlB = WlF + ((size_t)nt * 16) * 8 * 64 + (wn * 4) * 64 + lane;

    f32x4 acc[4][4];
#pragma unroll
    for (int i = 0; i < 4; ++i)
#pragma unroll
        for (int j = 0; j < 4; ++j) acc[i][j] = (f32x4){0.f, 0.f, 0.f, 0.f};

    uint4 ah[2][4], al[2][4], bh[2][4], bl[2][4];
    // prologue: step 0 frags
#pragma unroll
    for (int f = 0; f < 4; ++f) {
        ah[0][f] = XhB[f * 64];
        al[0][f] = XlB[f * 64];
        bh[0][f] = WhB[f * 64];
        bl[0][f] = WlB[f * 64];
    }

#pragma unroll
    for (int kc = 0; kc < 16; ++kc) {
        const int cur = kc & 1, nxt = cur ^ 1;
        // issue next-step loads first (16 loads in flight across the MFMAs)
        if (kc + 1 < 16) {
            const size_t off = (size_t)(kc + 1) * 512;
#pragma unroll
            for (int f = 0; f < 4; ++f) {
                ah[nxt][f] = XhB[off + f * 64];
                al[nxt][f] = XlB[off + f * 64];
                bh[nxt][f] = WhB[off + f * 64];
                bl[nxt][f] = WlB[off + f * 64];
            }
        }
        // 48 MFMA on current frags (compiler waits vmcnt for cur only)
#pragma unroll
        for (int fc = 0; fc < 4; ++fc) {
            const bf16x8 bH = __builtin_bit_cast(bf16x8, bh[cur][fc]);
            const bf16x8 bL = __builtin_bit_cast(bf16x8, bl[cur][fc]);
#pragma unroll
            for (int fr = 0; fr < 4; ++fr) {
                const bf16x8 aH = __builtin_bit_cast(bf16x8, ah[cur][fr]);
                const bf16x8 aL = __builtin_bit_cast(bf16x8, al[cur][fr]);
                acc[fr][fc] = __builtin_amdgcn_mfma_f32_16x16x32_bf16(aH, bH, acc[fr][fc], 0, 0, 0);
                acc[fr][fc] = __builtin_amdgcn_mfma_f32_16x16x32_bf16(aH, bL, acc[fr][fc], 0, 0, 0);
                acc[fr][fc] = __builtin_amdgcn_mfma_f32_16x16x32_bf16(aL, bH, acc[fr][fc], 0, 0, 0);
            }
        }
    }

    // ---- epilogue: p[row] = sum_col tanh(acc + uq[col]) * v[col]
    const int colbase = e0 + wn * 64;
#pragma unroll
    for (int fr = 0; fr < 4; ++fr) {
        float ps[4] = {0.f, 0.f, 0.f, 0.f};
#pragma unroll
        for (int fc = 0; fc < 4; ++fc) {
            const int col = colbase + fc * 16 + lo16;
            const float uqc = uqg[b * D + col];
            const float vc  = v[col];
#pragma unroll
            for (int i = 0; i < 4; ++i)
                ps[i] += fast_tanh(acc[fr][fc][i] + uqc) * vc;
        }
#pragma unroll
        for (int i = 0; i < 4; ++i) {
            float p = ps[i];
#pragma unroll
            for (int off = 8; off >= 1; off >>= 1) p += __shfl_xor(p, off, 16);
            if (lo16 == 0) scr[wn][wm * 64 + fr * 16 + hi4 * 4 + i] = p;
        }
    }
    __syncthreads();
    if (tid < 128)
        partialS[(size_t)nt * NROW + row0 + tid] = scr[0][tid] + scr[1][tid];
}

// ---------------------------------------------------------------- K3b: fallback GEMM (R13 structure, 163 us known-good)
__global__ __launch_bounds__(256, 4) void k_gemm(
    const float* __restrict__ X,
    const uint4* __restrict__ WhF,
    const uint4* __restrict__ WlF,
    const float* __restrict__ v,
    const float* __restrict__ uqg,
    float* __restrict__ partialS)   // [4][NROW]
{
    __shared__ uint4 Ah[2][4 * 128], Al[2][4 * 128];   // 32 KB
    __shared__ float scr[2][128];

    const int gidx = blockIdx.x;
    const int logical = (gidx & 7) * 256 + (gidx >> 3);
    const int mt = logical >> 2, nt = logical & 3;
    const int row0 = mt * 128, e0 = nt * 128;
    const int b = row0 >> 11;

    const int tid = threadIdx.x, lane = tid & 63, wid = tid >> 6;
    const int wm = wid >> 1, wn = wid & 1;
    const int lo16 = lane & 15, hi4 = lane >> 4;
    const int arow = tid & 127, akh = tid >> 7;

    const float4* Xg = (const float4*)(X + (size_t)(row0 + arow) * D + akh * 16);
    const uint4* WhB = WhF + ((size_t)nt * 16) * 8 * 64 + (wn * 4) * 64 + lane;
    const uint4* WlB = WlF + ((size_t)nt * 16) * 8 * 64 + (wn * 4) * 64 + lane;

    f32x4 acc[4][4];
#pragma unroll
    for (int i = 0; i < 4; ++i)
#pragma unroll
        for (int j = 0; j < 4; ++j) acc[i][j] = (f32x4){0.f, 0.f, 0.f, 0.f};

    float4 xr[2][4];
#pragma unroll
    for (int i = 0; i < 4; ++i) xr[0][i] = Xg[i];
#pragma unroll
    for (int i = 0; i < 4; ++i) xr[1][i] = Xg[8 + i];
    {
        uint4 hp, lp;
        cvt8(xr[0][0], xr[0][1], hp, lp);
        Ah[0][(akh * 2 + 0) * 128 + arow] = hp;
        Al[0][(akh * 2 + 0) * 128 + arow] = lp;
        cvt8(xr[0][2], xr[0][3], hp, lp);
        Ah[0][(akh * 2 + 1) * 128 + arow] = hp;
        Al[0][(akh * 2 + 1) * 128 + arow] = lp;
    }

#pragma unroll
    for (int kc = 0; kc < 16; ++kc) {
        const int cur = kc & 1, nxt = cur ^ 1;
        lds_barrier();

        uint4 bhr[4], blr[4];
        {
            const uint4* wh = WhB + (size_t)kc * 8 * 64;
            const uint4* wl = WlB + (size_t)kc * 8 * 64;
#pragma unroll
            for (int fc = 0; fc < 4; ++fc) {
                bhr[fc] = wh[fc * 64];
                blr[fc] = wl[fc * 64];
            }
        }

        if (kc + 1 < 16) {
            uint4 hp, lp;
            cvt8(xr[nxt][0], xr[nxt][1], hp, lp);
            Ah[nxt][(akh * 2 + 0) * 128 + arow] = hp;
            Al[nxt][(akh * 2 + 0) * 128 + arow] = lp;
            cvt8(xr[nxt][2], xr[nxt][3], hp, lp);
            Ah[nxt][(akh * 2 + 1) * 128 + arow] = hp;
            Al[nxt][(akh * 2 + 1) * 128 + arow] = lp;
        }

        bf16x8 aH[4], aL[4];
#pragma unroll
        for (int fr = 0; fr < 4; ++fr) {
            const int idx = hi4 * 128 + wm * 64 + fr * 16 + lo16;
            aH[fr] = __builtin_bit_cast(bf16x8, Ah[cur][idx]);
            aL[fr] = __builtin_bit_cast(bf16x8, Al[cur][idx]);
        }

#pragma unroll
        for (int fc = 0; fc < 4; ++fc) {
            const bf16x8 bH = __builtin_bit_cast(bf16x8, bhr[fc]);
            const bf16x8 bL = __builtin_bit_cast(bf16x8, blr[fc]);
#pragma unroll
            for (int fr = 0; fr < 4; ++fr) {
                acc[fr][fc] = __builtin_amdgcn_mfma_f32_16x16x32_bf16(aH[fr], bH, acc[fr][fc], 0, 0, 0);
                acc[fr][fc] = __builtin_amdgcn_mfma_f32_16x16x32_bf16(aH[fr], bL, acc[fr][fc], 0, 0, 0);
                acc[fr][fc] = __builtin_amdgcn_mfma_f32_16x16x32_bf16(aL[fr], bH, acc[fr][fc], 0, 0, 0);
            }
        }

        if (kc + 2 < 16) {
#pragma unroll
            for (int i = 0; i < 4; ++i) xr[cur][i] = Xg[(kc + 2) * 8 + i];
        }
    }

    const int colbase = e0 + wn * 64;
#pragma unroll
    for (int fr = 0; fr < 4; ++fr) {
        float ps[4] = {0.f, 0.f, 0.f, 0.f};
#pragma unroll
        for (int fc = 0; fc < 4; ++fc) {
            const int col = colbase + fc * 16 + lo16;
            const float uqc = uqg[b * D + col];
            const float vc  = v[col];
#pragma unroll
            for (int i = 0; i < 4; ++i)
                ps[i] += fast_tanh(acc[fr][fc][i] + uqc) * vc;
        }
#pragma unroll
        for (int i = 0; i < 4; ++i) {
            float p = ps[i];
#pragma unroll
            for (int off = 8; off >= 1; off >>= 1) p += __shfl_xor(p, off, 16);
            if (lo16 == 0) scr[wn][wm * 64 + fr * 16 + hi4 * 4 + i] = p;
        }
    }
    __syncthreads();
    if (tid < 128)
        partialS[(size_t)nt * NROW + row0 + tid] = scr[0][tid] + scr[1][tid];
}

// ---------------------------------------------------------------- K4: combine 4 partials + mask
__global__ void k_combine(const float* __restrict__ partialS,
                          const int* __restrict__ lengths,
                          float* __restrict__ score) {
    const int i = blockIdx.x * TPB + threadIdx.x;
    const int b = i >> 11, t = i & (T - 1);
    float s = partialS[i] + partialS[NROW + i] + partialS[2 * NROW + i] + partialS[3 * NROW + i];
    score[i] = (t < lengths[b]) ? s : NEG_SENTINEL;
}

// ---------------------------------------------------------------- K5: softmax over t per batch
__global__ void k_softmax(const float* __restrict__ score, float* __restrict__ weights) {
    const int b = blockIdx.x;
    const float* s = score + (size_t)b * T;
    float m = -INFINITY;
    for (int t = threadIdx.x; t < T; t += TPB) m = fmaxf(m, s[t]);
#pragma unroll
    for (int off = 32; off >= 1; off >>= 1) m = fmaxf(m, __shfl_xor(m, off, 64));
    __shared__ float redm[4];
    if ((threadIdx.x & 63) == 0) redm[threadIdx.x >> 6] = m;
    __syncthreads();
    m = fmaxf(fmaxf(redm[0], redm[1]), fmaxf(redm[2], redm[3]));

    float sum = 0.f;
    for (int t = threadIdx.x; t < T; t += TPB) sum += __expf(s[t] - m);
#pragma unroll
    for (int off = 32; off >= 1; off >>= 1) sum += __shfl_xor(sum, off, 64);
    __shared__ float reds[4];
    if ((threadIdx.x & 63) == 0) reds[threadIdx.x >> 6] = sum;
    __syncthreads();
    const float inv = 1.f / (reds[0] + reds[1] + reds[2] + reds[3]);

    for (int t = threadIdx.x; t < T; t += TPB)
        weights[(size_t)b * T + t] = __expf(s[t] - m) * inv;
}

// ---------------------------------------------------------------- K6: partial expectation (16 chunks of 128 t)
__global__ void k_exp_partial(const float* __restrict__ X, const float* __restrict__ wts,
                              float* __restrict__ part) {
    const int b = blockIdx.x >> 4;
    const int c = blockIdx.x & 15;
    const int t0 = c * 128;
    const int d0 = threadIdx.x * 4;   // 128 threads x float4
    const float* Xb = X + ((size_t)b * T + t0) * D + d0;
    const float* wb = wts + (size_t)b * T + t0;
    float4 a = {0.f, 0.f, 0.f, 0.f};
    for (int t = 0; t < 128; ++t) {
        const float wgt = wb[t];
        const float4 x = *(const float4*)(Xb + (size_t)t * D);
        a.x += wgt * x.x; a.y += wgt * x.y; a.z += wgt * x.z; a.w += wgt * x.w;
    }
    *(float4*)(part + ((size_t)(b * 16 + c)) * D + d0) = a;
}

// ---------------------------------------------------------------- K7: reduce 16 partials
__global__ void k_exp_reduce(const float* __restrict__ part, float* __restrict__ out) {
    const int i = blockIdx.x * TPB + threadIdx.x;   // B*D
    const int b = i >> 9, d = i & 511;
    float a = 0.f;
#pragma unroll
    for (int c = 0; c < 16; ++c) a += part[((size_t)(b * 16 + c)) * D + d];
    out[i] = a;
}

// ----------------------------------------------------------------
extern "C" void kernel_launch(void* const* d_in, const int* in_sizes, int n_in,
                              void* d_out, int out_size, void* d_ws, size_t ws_size,
                              hipStream_t stream) {
    const float* X      = (const float*)d_in[0];
    const float* query  = (const float*)d_in[1];
    const int*   len    = (const int*)  d_in[2];
    const float* w      = (const float*)d_in[3];
    const float* u      = (const float*)d_in[4];
    const float* v      = (const float*)d_in[5];

    float* out     = (float*)d_out;
    float* score   = out;
    float* weights = out + (size_t)B * T;
    float* expec   = out + (size_t)2 * B * T;

    // ws layout (bytes):
    //   uq       : 65,536
    //   partialS : 1,048,576   (aliased later by 'part')
    //   WhF/WlF  : 524,288 x2
    //   XhF/XlF  : 67,108,864 x2   (fast path only)
    float* uq       = (float*)d_ws;
    float* partialS = uq + (size_t)B * D;
    uint4* WhF      = (uint4*)(partialS + (size_t)4 * NROW);
    uint4* WlF      = WhF + 32768;
    uint4* XhF      = WlF + 32768;
    uint4* XlF      = XhF + (size_t)NROW * 64;
    float* part     = partialS;

    const size_t WS_FAST = (size_t)65536 + 1048576 + 2 * 524288 + 2 * 67108864;
    const bool fast = ws_size >= WS_FAST;

    k_uq         <<<B,            TPB, 0, stream>>>(query, u, uq);
    k_convW      <<<128,          TPB, 0, stream>>>(w, WhF, WlF);
    if (fast) {
        k_convX      <<<NROW / 16,  TPB, 0, stream>>>(X, XhF, XlF);
        k_gemm_stream<<<2048,       TPB, 0, stream>>>(XhF, XlF, WhF, WlF, v, uq, partialS);
    } else {
        k_gemm       <<<2048,       TPB, 0, stream>>>(X, WhF, WlF, v, uq, partialS);
    }
    k_combine    <<<NROW / TPB,   TPB, 0, stream>>>(partialS, len, score);
    k_softmax    <<<B,            TPB, 0, stream>>>(score, weights);
    k_exp_partial<<<B * 16,       128, 0, stream>>>(X, weights, part);
    k_exp_reduce <<<B * D / TPB,  TPB, 0, stream>>>(part, expec);
}

// Round 19
// 183.798 us; speedup vs baseline: 1.3106x; 1.1262x over previous
//
#include <hip/hip_runtime.h>
#include <math.h>

// Bahdanau attention: B=32, T=2048, D=512, Q=512, fp32.
// out = [score (B*T), weights (B*T), expectation (B*D)] concatenated.
// Masked positions: finite sentinel -1e30 (ref has -inf; |inf diff| <= inf thr,
// exp underflows to 0 identically).
//
// R19: CONSOLIDATION on the best-known total (R13 = 185.7 us).
// - The preconverted-X streaming path is removed: its GEMM (102 us) + convX
//   tax (~80 us, mixed-R/W HBM floor) + L3-evicted tail = 206+ us, worse in
//   total than R13's fused 163 us GEMM despite 44% vs 26% MfmaUtil.
// - k_combine + k_softmax fused (scores staged in LDS; one fewer launch,
//   no partialS re-read, no score re-read).
// GEMM: split-bf16 MFMA (hi*hi+hi*lo+lo*hi in fp32), A converted in-kernel
// via v_cvt_pk_bf16_f32 -> LDS double-buffer, one LDS-only barrier/K-step
// (vmem stays in flight), W preconverted to fragment layout (L2-resident),
// XCD-bijective block swizzle, 4 blocks/CU.

#define TPB 256
constexpr int B = 32, T = 2048, D = 512, Qd = 512;
constexpr int NROW = B * T;
#define NEG_SENTINEL (-1e30f)

typedef __attribute__((ext_vector_type(8))) short bf16x8;
typedef __attribute__((ext_vector_type(4))) float f32x4;

// LDS-only barrier: ds ops drained, vmem stays in flight.
__device__ __forceinline__ void lds_barrier() {
    asm volatile("s_waitcnt lgkmcnt(0)" ::: "memory");
    __builtin_amdgcn_s_barrier();
}

// HW packed fp32->bf16 RNE: result.lo16 = bf16(a), result.hi16 = bf16(b)
__device__ __forceinline__ unsigned cvtpk(float a, float b) {
    unsigned r;
    asm("v_cvt_pk_bf16_f32 %0, %1, %2" : "=v"(r) : "v"(a), "v"(b));
    return r;
}
// split two floats into packed-hi (return) and packed-lo bf16 pairs
__device__ __forceinline__ unsigned packsplit(float f0, float f1, unsigned& lopack) {
    unsigned hp = cvtpk(f0, f1);
    float h0 = __builtin_bit_cast(float, hp << 16);
    float h1 = __builtin_bit_cast(float, hp & 0xFFFF0000u);
    lopack = cvtpk(f0 - h0, f1 - h1);
    return hp;
}
__device__ __forceinline__ void cvt8(const float4 a, const float4 b, uint4& hi, uint4& lo) {
    hi.x = packsplit(a.x, a.y, lo.x);
    hi.y = packsplit(a.z, a.w, lo.y);
    hi.z = packsplit(b.x, b.y, lo.z);
    hi.w = packsplit(b.z, b.w, lo.w);
}
// fast tanh: saturating exp form, |err| ~ 1e-7
__device__ __forceinline__ float fast_tanh(float x) {
    float a = fabsf(x);
    float e = __expf(-2.f * a);
    float t = (1.f - e) / (1.f + e);
    return copysignf(t, x);
}

// ---------------------------------------------------------------- K1: uq[b][e]
__global__ void k_uq(const float* __restrict__ query, const float* __restrict__ u,
                     float* __restrict__ uq) {
    int b = blockIdx.x;
    __shared__ float q_s[Qd];
    for (int i = threadIdx.x; i < Qd; i += TPB) q_s[i] = query[b * Qd + i];
    __syncthreads();
    for (int e = threadIdx.x; e < D; e += TPB) {
        const float4* urow = (const float4*)(u + (size_t)e * Qd);
        float acc = 0.f;
        for (int q4 = 0; q4 < Qd / 4; ++q4) {
            float4 uu = urow[q4];
            float4 qq = *(const float4*)(q_s + q4 * 4);
            acc += uu.x * qq.x + uu.y * qq.y + uu.z * qq.z + uu.w * qq.w;
        }
        uq[b * D + e] = acc;
    }
}

// ---------------------------------------------------------------- K2: W -> split-bf16 fragment layout
// idx16 = ((nt*16 + kc)*8 + cb)*64 + hi4*16 + lo16
//   e = nt*128 + cb*16 + lo16, d0 = kc*32 + hi4*8
// GEMM lane l reads position l (identity order -> coalesced).
__global__ void k_convW(const float* __restrict__ W,
                        uint4* __restrict__ WhF, uint4* __restrict__ WlF) {
    const int g = blockIdx.x * 256 + threadIdx.x;   // 0..32767
    const int e = g >> 6, s = g & 63;               // d0 = s*8
    const float4* src = (const float4*)(W + (size_t)e * D + s * 8);
    float4 a = src[0], bq = src[1];
    uint4 hi, lo;
    cvt8(a, bq, hi, lo);
    const int nt = e >> 7, cb = (e >> 4) & 7, lo16 = e & 15;
    const int kc = s >> 2, hi4 = s & 3;
    const size_t idx = ((size_t)(nt * 16 + kc) * 8 + cb) * 64 + hi4 * 16 + lo16;
    WhF[idx] = hi;
    WlF[idx] = lo;
}

// ---------------------------------------------------------------- K3: split-bf16 MFMA GEMM + fused tanh*v
// Block tile 128x128, BK=32, 4 waves (2m x 2n), wave 64x64 = 4x4 frags of
// 16x16x32, 3 products in fp32 acc. A: regs -> cvt_pk -> LDS double-buffer,
// one LDS-only barrier per K-step. B: preconverted frag-layout, global->reg
// (L2-resident). 4 blocks/CU.
__global__ __launch_bounds__(256, 4) void k_gemm(
    const float* __restrict__ X,
    const uint4* __restrict__ WhF,
    const uint4* __restrict__ WlF,
    const float* __restrict__ v,
    const float* __restrict__ uqg,
    float* __restrict__ partialS)   // [4][NROW]
{
    __shared__ uint4 Ah[2][4 * 128], Al[2][4 * 128];   // 32 KB
    __shared__ float scr[2][128];

    // XCD-bijective swizzle (2048 % 8 == 0)
    const int gidx = blockIdx.x;
    const int logical = (gidx & 7) * 256 + (gidx >> 3);
    const int mt = logical >> 2, nt = logical & 3;
    const int row0 = mt * 128, e0 = nt * 128;
    const int b = row0 >> 11;

    const int tid = threadIdx.x, lane = tid & 63, wid = tid >> 6;
    const int wm = wid >> 1, wn = wid & 1;
    const int lo16 = lane & 15, hi4 = lane >> 4;
    const int arow = tid & 127, akh = tid >> 7;

    const float4* Xg = (const float4*)(X + (size_t)(row0 + arow) * D + akh * 16);
    const uint4* WhB = WhF + ((size_t)nt * 16) * 8 * 64 + (wn * 4) * 64 + lane;
    const uint4* WlB = WlF + ((size_t)nt * 16) * 8 * 64 + (wn * 4) * 64 + lane;

    f32x4 acc[4][4];
#pragma unroll
    for (int i = 0; i < 4; ++i)
#pragma unroll
        for (int j = 0; j < 4; ++j) acc[i][j] = (f32x4){0.f, 0.f, 0.f, 0.f};

    // prologue: X(0)->xr[0], X(1)->xr[1]; convert X(0) -> buf0
    float4 xr[2][4];
#pragma unroll
    for (int i = 0; i < 4; ++i) xr[0][i] = Xg[i];
#pragma unroll
    for (int i = 0; i < 4; ++i) xr[1][i] = Xg[8 + i];
    {
        uint4 hp, lp;
        cvt8(xr[0][0], xr[0][1], hp, lp);
        Ah[0][(akh * 2 + 0) * 128 + arow] = hp;
        Al[0][(akh * 2 + 0) * 128 + arow] = lp;
        cvt8(xr[0][2], xr[0][3], hp, lp);
        Ah[0][(akh * 2 + 1) * 128 + arow] = hp;
        Al[0][(akh * 2 + 1) * 128 + arow] = lp;
    }

#pragma unroll
    for (int kc = 0; kc < 16; ++kc) {
        const int cur = kc & 1, nxt = cur ^ 1;
        lds_barrier();   // buf[cur] writes visible; vmem stays in flight

        // B fragment loads for kc (consumed after convert)
        uint4 bhr[4], blr[4];
        {
            const uint4* wh = WhB + (size_t)kc * 8 * 64;
            const uint4* wl = WlB + (size_t)kc * 8 * 64;
#pragma unroll
            for (int fc = 0; fc < 4; ++fc) {
                bhr[fc] = wh[fc * 64];
                blr[fc] = wl[fc * 64];
            }
        }

        // convert X(kc+1) (loaded >=1 iter ago) -> buf[nxt]; overlaps B latency
        if (kc + 1 < 16) {
            uint4 hp, lp;
            cvt8(xr[nxt][0], xr[nxt][1], hp, lp);
            Ah[nxt][(akh * 2 + 0) * 128 + arow] = hp;
            Al[nxt][(akh * 2 + 0) * 128 + arow] = lp;
            cvt8(xr[nxt][2], xr[nxt][3], hp, lp);
            Ah[nxt][(akh * 2 + 1) * 128 + arow] = hp;
            Al[nxt][(akh * 2 + 1) * 128 + arow] = lp;
        }

        // A fragments from buf[cur]
        bf16x8 aH[4], aL[4];
#pragma unroll
        for (int fr = 0; fr < 4; ++fr) {
            const int idx = hi4 * 128 + wm * 64 + fr * 16 + lo16;
            aH[fr] = __builtin_bit_cast(bf16x8, Ah[cur][idx]);
            aL[fr] = __builtin_bit_cast(bf16x8, Al[cur][idx]);
        }

#pragma unroll
        for (int fc = 0; fc < 4; ++fc) {
            const bf16x8 bH = __builtin_bit_cast(bf16x8, bhr[fc]);
            const bf16x8 bL = __builtin_bit_cast(bf16x8, blr[fc]);
#pragma unroll
            for (int fr = 0; fr < 4; ++fr) {
                acc[fr][fc] = __builtin_amdgcn_mfma_f32_16x16x32_bf16(aH[fr], bH, acc[fr][fc], 0, 0, 0);
                acc[fr][fc] = __builtin_amdgcn_mfma_f32_16x16x32_bf16(aH[fr], bL, acc[fr][fc], 0, 0, 0);
                acc[fr][fc] = __builtin_amdgcn_mfma_f32_16x16x32_bf16(aL[fr], bH, acc[fr][fc], 0, 0, 0);
            }
        }

        // prefetch X(kc+2) into xr[cur]; stays in flight across next barrier
        if (kc + 2 < 16) {
#pragma unroll
            for (int i = 0; i < 4; ++i) xr[cur][i] = Xg[(kc + 2) * 8 + i];
        }
    }

    // ---- epilogue: p[row] = sum_col tanh(acc + uq[col]) * v[col]
    const int colbase = e0 + wn * 64;
#pragma unroll
    for (int fr = 0; fr < 4; ++fr) {
        float ps[4] = {0.f, 0.f, 0.f, 0.f};
#pragma unroll
        for (int fc = 0; fc < 4; ++fc) {
            const int col = colbase + fc * 16 + lo16;
            const float uqc = uqg[b * D + col];
            const float vc  = v[col];
#pragma unroll
            for (int i = 0; i < 4; ++i)
                ps[i] += fast_tanh(acc[fr][fc][i] + uqc) * vc;
        }
#pragma unroll
        for (int i = 0; i < 4; ++i) {
            float p = ps[i];
#pragma unroll
            for (int off = 8; off >= 1; off >>= 1) p += __shfl_xor(p, off, 16);
            if (lo16 == 0) scr[wn][wm * 64 + fr * 16 + hi4 * 4 + i] = p;
        }
    }
    __syncthreads();
    if (tid < 128)
        partialS[(size_t)nt * NROW + row0 + tid] = scr[0][tid] + scr[1][tid];
}

// ---------------------------------------------------------------- K4: fused combine + mask + softmax
// One block per batch b (32 blocks, 256 thr). Scores staged in 8 KB LDS:
// partialS read once, score written once, weights written once.
__global__ void k_csm(const float* __restrict__ partialS,
                      const int* __restrict__ lengths,
                      float* __restrict__ score,
                      float* __restrict__ weights) {
    __shared__ float s_s[T];          // 8 KB
    __shared__ float redm[4], reds[4];
    const int b = blockIdx.x;
    const int len = lengths[b];
    const size_t base = (size_t)b * T;

    float m = -INFINITY;
    for (int t = threadIdx.x; t < T; t += TPB) {
        const size_t i = base + t;
        float s = partialS[i] + partialS[NROW + i]
                + partialS[2 * NROW + i] + partialS[3 * NROW + i];
        s = (t < len) ? s : NEG_SENTINEL;
        score[i] = s;
        s_s[t] = s;
        m = fmaxf(m, s);
    }
#pragma unroll
    for (int off = 32; off >= 1; off >>= 1) m = fmaxf(m, __shfl_xor(m, off, 64));
    if ((threadIdx.x & 63) == 0) redm[threadIdx.x >> 6] = m;
    __syncthreads();
    m = fmaxf(fmaxf(redm[0], redm[1]), fmaxf(redm[2], redm[3]));

    float sum = 0.f;
    for (int t = threadIdx.x; t < T; t += TPB) sum += __expf(s_s[t] - m);
#pragma unroll
    for (int off = 32; off >= 1; off >>= 1) sum += __shfl_xor(sum, off, 64);
    if ((threadIdx.x & 63) == 0) reds[threadIdx.x >> 6] = sum;
    __syncthreads();
    const float inv = 1.f / (reds[0] + reds[1] + reds[2] + reds[3]);

    for (int t = threadIdx.x; t < T; t += TPB)
        weights[base + t] = __expf(s_s[t] - m) * inv;
}

// ---------------------------------------------------------------- K5: partial expectation (16 chunks of 128 t)
__global__ void k_exp_partial(const float* __restrict__ X, const float* __restrict__ wts,
                              float* __restrict__ part) {
    const int b = blockIdx.x >> 4;
    const int c = blockIdx.x & 15;
    const int t0 = c * 128;
    const int d0 = threadIdx.x * 4;   // 128 threads x float4
    const float* Xb = X + ((size_t)b * T + t0) * D + d0;
    const float* wb = wts + (size_t)b * T + t0;
    float4 a = {0.f, 0.f, 0.f, 0.f};
    for (int t = 0; t < 128; ++t) {
        const float wgt = wb[t];
        const float4 x = *(const float4*)(Xb + (size_t)t * D);
        a.x += wgt * x.x; a.y += wgt * x.y; a.z += wgt * x.z; a.w += wgt * x.w;
    }
    *(float4*)(part + ((size_t)(b * 16 + c)) * D + d0) = a;
}

// ---------------------------------------------------------------- K6: reduce 16 partials
__global__ void k_exp_reduce(const float* __restrict__ part, float* __restrict__ out) {
    const int i = blockIdx.x * TPB + threadIdx.x;   // B*D
    const int b = i >> 9, d = i & 511;
    float a = 0.f;
#pragma unroll
    for (int c = 0; c < 16; ++c) a += part[((size_t)(b * 16 + c)) * D + d];
    out[i] = a;
}

// ----------------------------------------------------------------
extern "C" void kernel_launch(void* const* d_in, const int* in_sizes, int n_in,
                              void* d_out, int out_size, void* d_ws, size_t ws_size,
                              hipStream_t stream) {
    const float* X      = (const float*)d_in[0];
    const float* query  = (const float*)d_in[1];
    const int*   len    = (const int*)  d_in[2];
    const float* w      = (const float*)d_in[3];
    const float* u      = (const float*)d_in[4];
    const float* v      = (const float*)d_in[5];

    float* out     = (float*)d_out;
    float* score   = out;
    float* weights = out + (size_t)B * T;
    float* expec   = out + (size_t)2 * B * T;

    // ws layout: uq 64K | partialS 1M | WhF 512K | WlF 512K  (~2.1 MB)
    float* uq       = (float*)d_ws;
    float* partialS = uq + (size_t)B * D;                       // 262144 floats
    uint4* WhF      = (uint4*)(partialS + (size_t)4 * NROW);    // 32768 uint4
    uint4* WlF      = WhF + 32768;
    float* part     = partialS;   // alias: 16*B*D floats = 1MB, partialS dead by then

    k_uq         <<<B,            TPB, 0, stream>>>(query, u, uq);
    k_convW      <<<128,          TPB, 0, stream>>>(w, WhF, WlF);
    k_gemm       <<<2048,         TPB, 0, stream>>>(X, WhF, WlF, v, uq, partialS);
    k_csm        <<<B,            TPB, 0, stream>>>(partialS, len, score, weights);
    k_exp_partial<<<B * 16,       128, 0, stream>>>(X, weights, part);
    k_exp_reduce <<<B * D / TPB,  TPB, 0, stream>>>(part, expec);
}

// Round 20
// 176.881 us; speedup vs baseline: 1.3619x; 1.0391x over previous
//
#include <hip/hip_runtime.h>
#include <math.h>

// Bahdanau attention: B=32, T=2048, D=512, Q=512, fp32.
// out = [score (B*T), weights (B*T), expectation (B*D)] concatenated.
// Masked positions: finite sentinel -1e30 (ref has -inf; |inf diff| <= inf thr,
// exp underflows to 0 identically).
//
// R20 = R19 + B-hi register double-buffer across K-steps (bhr(kc+1) issued
// before the MFMA cluster, +16 VGPR) and MFMA cluster split into 3 passes
// (pass1 aHxbH covers the in-step B-lo load latency). launch_bounds(256,3)
// so the extra live regs don't spill (R19 was at exactly the (256,4)
// 128-unified-reg cap: 64 VGPR + 64 AGPR).

#define TPB 256
constexpr int B = 32, T = 2048, D = 512, Qd = 512;
constexpr int NROW = B * T;
#define NEG_SENTINEL (-1e30f)

typedef __attribute__((ext_vector_type(8))) short bf16x8;
typedef __attribute__((ext_vector_type(4))) float f32x4;

// LDS-only barrier: ds ops drained, vmem stays in flight.
__device__ __forceinline__ void lds_barrier() {
    asm volatile("s_waitcnt lgkmcnt(0)" ::: "memory");
    __builtin_amdgcn_s_barrier();
}

// HW packed fp32->bf16 RNE: result.lo16 = bf16(a), result.hi16 = bf16(b)
__device__ __forceinline__ unsigned cvtpk(float a, float b) {
    unsigned r;
    asm("v_cvt_pk_bf16_f32 %0, %1, %2" : "=v"(r) : "v"(a), "v"(b));
    return r;
}
// split two floats into packed-hi (return) and packed-lo bf16 pairs
__device__ __forceinline__ unsigned packsplit(float f0, float f1, unsigned& lopack) {
    unsigned hp = cvtpk(f0, f1);
    float h0 = __builtin_bit_cast(float, hp << 16);
    float h1 = __builtin_bit_cast(float, hp & 0xFFFF0000u);
    lopack = cvtpk(f0 - h0, f1 - h1);
    return hp;
}
__device__ __forceinline__ void cvt8(const float4 a, const float4 b, uint4& hi, uint4& lo) {
    hi.x = packsplit(a.x, a.y, lo.x);
    hi.y = packsplit(a.z, a.w, lo.y);
    hi.z = packsplit(b.x, b.y, lo.z);
    hi.w = packsplit(b.z, b.w, lo.w);
}
// fast tanh: saturating exp form, |err| ~ 1e-7
__device__ __forceinline__ float fast_tanh(float x) {
    float a = fabsf(x);
    float e = __expf(-2.f * a);
    float t = (1.f - e) / (1.f + e);
    return copysignf(t, x);
}

// ---------------------------------------------------------------- K1: uq[b][e]
__global__ void k_uq(const float* __restrict__ query, const float* __restrict__ u,
                     float* __restrict__ uq) {
    int b = blockIdx.x;
    __shared__ float q_s[Qd];
    for (int i = threadIdx.x; i < Qd; i += TPB) q_s[i] = query[b * Qd + i];
    __syncthreads();
    for (int e = threadIdx.x; e < D; e += TPB) {
        const float4* urow = (const float4*)(u + (size_t)e * Qd);
        float acc = 0.f;
        for (int q4 = 0; q4 < Qd / 4; ++q4) {
            float4 uu = urow[q4];
            float4 qq = *(const float4*)(q_s + q4 * 4);
            acc += uu.x * qq.x + uu.y * qq.y + uu.z * qq.z + uu.w * qq.w;
        }
        uq[b * D + e] = acc;
    }
}

// ---------------------------------------------------------------- K2: W -> split-bf16 fragment layout
// idx16 = ((nt*16 + kc)*8 + cb)*64 + hi4*16 + lo16
//   e = nt*128 + cb*16 + lo16, d0 = kc*32 + hi4*8
// GEMM lane l reads position l (identity order -> coalesced).
__global__ void k_convW(const float* __restrict__ W,
                        uint4* __restrict__ WhF, uint4* __restrict__ WlF) {
    const int g = blockIdx.x * 256 + threadIdx.x;   // 0..32767
    const int e = g >> 6, s = g & 63;               // d0 = s*8
    const float4* src = (const float4*)(W + (size_t)e * D + s * 8);
    float4 a = src[0], bq = src[1];
    uint4 hi, lo;
    cvt8(a, bq, hi, lo);
    const int nt = e >> 7, cb = (e >> 4) & 7, lo16 = e & 15;
    const int kc = s >> 2, hi4 = s & 3;
    const size_t idx = ((size_t)(nt * 16 + kc) * 8 + cb) * 64 + hi4 * 16 + lo16;
    WhF[idx] = hi;
    WlF[idx] = lo;
}

// ---------------------------------------------------------------- K3: split-bf16 MFMA GEMM + fused tanh*v
// Block tile 128x128, BK=32, 4 waves (2m x 2n), wave 64x64 = 4x4 frags of
// 16x16x32, 3 products in fp32 acc. A: regs -> cvt_pk -> LDS double-buffer,
// one LDS-only barrier per K-step. B-hi: register double-buffer across
// K-steps (prefetched under MFMA). B-lo: loaded in-step, consumed in pass2
// (covered by pass1's 16 MFMAs). 3 blocks/CU.
__global__ __launch_bounds__(256, 3) void k_gemm(
    const float* __restrict__ X,
    const uint4* __restrict__ WhF,
    const uint4* __restrict__ WlF,
    const float* __restrict__ v,
    const float* __restrict__ uqg,
    float* __restrict__ partialS)   // [4][NROW]
{
    __shared__ uint4 Ah[2][4 * 128], Al[2][4 * 128];   // 32 KB
    __shared__ float scr[2][128];

    // XCD-bijective swizzle (2048 % 8 == 0)
    const int gidx = blockIdx.x;
    const int logical = (gidx & 7) * 256 + (gidx >> 3);
    const int mt = logical >> 2, nt = logical & 3;
    const int row0 = mt * 128, e0 = nt * 128;
    const int b = row0 >> 11;

    const int tid = threadIdx.x, lane = tid & 63, wid = tid >> 6;
    const int wm = wid >> 1, wn = wid & 1;
    const int lo16 = lane & 15, hi4 = lane >> 4;
    const int arow = tid & 127, akh = tid >> 7;

    const float4* Xg = (const float4*)(X + (size_t)(row0 + arow) * D + akh * 16);
    const uint4* WhB = WhF + ((size_t)nt * 16) * 8 * 64 + (wn * 4) * 64 + lane;
    const uint4* WlB = WlF + ((size_t)nt * 16) * 8 * 64 + (wn * 4) * 64 + lane;

    f32x4 acc[4][4];
#pragma unroll
    for (int i = 0; i < 4; ++i)
#pragma unroll
        for (int j = 0; j < 4; ++j) acc[i][j] = (f32x4){0.f, 0.f, 0.f, 0.f};

    // prologue: X(0)->xr[0], X(1)->xr[1]; convert X(0) -> buf0; B-hi(0) -> regs
    float4 xr[2][4];
#pragma unroll
    for (int i = 0; i < 4; ++i) xr[0][i] = Xg[i];
#pragma unroll
    for (int i = 0; i < 4; ++i) xr[1][i] = Xg[8 + i];
    uint4 bhr[4];
#pragma unroll
    for (int fc = 0; fc < 4; ++fc) bhr[fc] = WhB[fc * 64];
    {
        uint4 hp, lp;
        cvt8(xr[0][0], xr[0][1], hp, lp);
        Ah[0][(akh * 2 + 0) * 128 + arow] = hp;
        Al[0][(akh * 2 + 0) * 128 + arow] = lp;
        cvt8(xr[0][2], xr[0][3], hp, lp);
        Ah[0][(akh * 2 + 1) * 128 + arow] = hp;
        Al[0][(akh * 2 + 1) * 128 + arow] = lp;
    }

#pragma unroll
    for (int kc = 0; kc < 16; ++kc) {
        const int cur = kc & 1, nxt = cur ^ 1;
        lds_barrier();   // buf[cur] writes visible; vmem stays in flight

        // B-lo loads for kc (consumed in pass2; covered by pass1 MFMAs)
        uint4 blr[4];
        {
            const uint4* wl = WlB + (size_t)kc * 512;
#pragma unroll
            for (int fc = 0; fc < 4; ++fc) blr[fc] = wl[fc * 64];
        }

        // convert X(kc+1) (loaded >=1 iter ago) -> buf[nxt]
        if (kc + 1 < 16) {
            uint4 hp, lp;
            cvt8(xr[nxt][0], xr[nxt][1], hp, lp);
            Ah[nxt][(akh * 2 + 0) * 128 + arow] = hp;
            Al[nxt][(akh * 2 + 0) * 128 + arow] = lp;
            cvt8(xr[nxt][2], xr[nxt][3], hp, lp);
            Ah[nxt][(akh * 2 + 1) * 128 + arow] = hp;
            Al[nxt][(akh * 2 + 1) * 128 + arow] = lp;
        }

        // A fragments from buf[cur]
        bf16x8 aH[4], aL[4];
#pragma unroll
        for (int fr = 0; fr < 4; ++fr) {
            const int idx = hi4 * 128 + wm * 64 + fr * 16 + lo16;
            aH[fr] = __builtin_bit_cast(bf16x8, Ah[cur][idx]);
            aL[fr] = __builtin_bit_cast(bf16x8, Al[cur][idx]);
        }

        // stash current B-hi, prefetch B-hi(kc+1) (lives across MFMA cluster)
        bf16x8 bHc[4];
#pragma unroll
        for (int fc = 0; fc < 4; ++fc) bHc[fc] = __builtin_bit_cast(bf16x8, bhr[fc]);
        if (kc + 1 < 16) {
            const uint4* wh = WhB + (size_t)(kc + 1) * 512;
#pragma unroll
            for (int fc = 0; fc < 4; ++fc) bhr[fc] = wh[fc * 64];
        }

        // pass1: aH x bH (B-hi arrived last step -> no wait)
#pragma unroll
        for (int fc = 0; fc < 4; ++fc)
#pragma unroll
            for (int fr = 0; fr < 4; ++fr)
                acc[fr][fc] = __builtin_amdgcn_mfma_f32_16x16x32_bf16(aH[fr], bHc[fc], acc[fr][fc], 0, 0, 0);
        // pass2: aH x bL (blr issued ~pass1 ago -> covered)
#pragma unroll
        for (int fc = 0; fc < 4; ++fc) {
            const bf16x8 bL = __builtin_bit_cast(bf16x8, blr[fc]);
#pragma unroll
            for (int fr = 0; fr < 4; ++fr)
                acc[fr][fc] = __builtin_amdgcn_mfma_f32_16x16x32_bf16(aH[fr], bL, acc[fr][fc], 0, 0, 0);
        }
        // pass3: aL x bH
#pragma unroll
        for (int fc = 0; fc < 4; ++fc)
#pragma unroll
            for (int fr = 0; fr < 4; ++fr)
                acc[fr][fc] = __builtin_amdgcn_mfma_f32_16x16x32_bf16(aL[fr], bHc[fc], acc[fr][fc], 0, 0, 0);

        // prefetch X(kc+2) into xr[cur]; stays in flight across next barrier
        if (kc + 2 < 16) {
#pragma unroll
            for (int i = 0; i < 4; ++i) xr[cur][i] = Xg[(kc + 2) * 8 + i];
        }
    }

    // ---- epilogue: p[row] = sum_col tanh(acc + uq[col]) * v[col]
    const int colbase = e0 + wn * 64;
#pragma unroll
    for (int fr = 0; fr < 4; ++fr) {
        float ps[4] = {0.f, 0.f, 0.f, 0.f};
#pragma unroll
        for (int fc = 0; fc < 4; ++fc) {
            const int col = colbase + fc * 16 + lo16;
            const float uqc = uqg[b * D + col];
            const float vc  = v[col];
#pragma unroll
            for (int i = 0; i < 4; ++i)
                ps[i] += fast_tanh(acc[fr][fc][i] + uqc) * vc;
        }
#pragma unroll
        for (int i = 0; i < 4; ++i) {
            float p = ps[i];
#pragma unroll
            for (int off = 8; off >= 1; off >>= 1) p += __shfl_xor(p, off, 16);
            if (lo16 == 0) scr[wn][wm * 64 + fr * 16 + hi4 * 4 + i] = p;
        }
    }
    __syncthreads();
    if (tid < 128)
        partialS[(size_t)nt * NROW + row0 + tid] = scr[0][tid] + scr[1][tid];
}

// ---------------------------------------------------------------- K4: fused combine + mask + softmax
__global__ void k_csm(const float* __restrict__ partialS,
                      const int* __restrict__ lengths,
                      float* __restrict__ score,
                      float* __restrict__ weights) {
    __shared__ float s_s[T];          // 8 KB
    __shared__ float redm[4], reds[4];
    const int b = blockIdx.x;
    const int len = lengths[b];
    const size_t base = (size_t)b * T;

    float m = -INFINITY;
    for (int t = threadIdx.x; t < T; t += TPB) {
        const size_t i = base + t;
        float s = partialS[i] + partialS[NROW + i]
                + partialS[2 * NROW + i] + partialS[3 * NROW + i];
        s = (t < len) ? s : NEG_SENTINEL;
        score[i] = s;
        s_s[t] = s;
        m = fmaxf(m, s);
    }
#pragma unroll
    for (int off = 32; off >= 1; off >>= 1) m = fmaxf(m, __shfl_xor(m, off, 64));
    if ((threadIdx.x & 63) == 0) redm[threadIdx.x >> 6] = m;
    __syncthreads();
    m = fmaxf(fmaxf(redm[0], redm[1]), fmaxf(redm[2], redm[3]));

    float sum = 0.f;
    for (int t = threadIdx.x; t < T; t += TPB) sum += __expf(s_s[t] - m);
#pragma unroll
    for (int off = 32; off >= 1; off >>= 1) sum += __shfl_xor(sum, off, 64);
    if ((threadIdx.x & 63) == 0) reds[threadIdx.x >> 6] = sum;
    __syncthreads();
    const float inv = 1.f / (reds[0] + reds[1] + reds[2] + reds[3]);

    for (int t = threadIdx.x; t < T; t += TPB)
        weights[base + t] = __expf(s_s[t] - m) * inv;
}

// ---------------------------------------------------------------- K5: partial expectation (16 chunks of 128 t)
__global__ void k_exp_partial(const float* __restrict__ X, const float* __restrict__ wts,
                              float* __restrict__ part) {
    const int b = blockIdx.x >> 4;
    const int c = blockIdx.x & 15;
    const int t0 = c * 128;
    const int d0 = threadIdx.x * 4;   // 128 threads x float4
    const float* Xb = X + ((size_t)b * T + t0) * D + d0;
    const float* wb = wts + (size_t)b * T + t0;
    float4 a = {0.f, 0.f, 0.f, 0.f};
    for (int t = 0; t < 128; ++t) {
        const float wgt = wb[t];
        const float4 x = *(const float4*)(Xb + (size_t)t * D);
        a.x += wgt * x.x; a.y += wgt * x.y; a.z += wgt * x.z; a.w += wgt * x.w;
    }
    *(float4*)(part + ((size_t)(b * 16 + c)) * D + d0) = a;
}

// ---------------------------------------------------------------- K6: reduce 16 partials
__global__ void k_exp_reduce(const float* __restrict__ part, float* __restrict__ out) {
    const int i = blockIdx.x * TPB + threadIdx.x;   // B*D
    const int b = i >> 9, d = i & 511;
    float a = 0.f;
#pragma unroll
    for (int c = 0; c < 16; ++c) a += part[((size_t)(b * 16 + c)) * D + d];
    out[i] = a;
}

// ----------------------------------------------------------------
extern "C" void kernel_launch(void* const* d_in, const int* in_sizes, int n_in,
                              void* d_out, int out_size, void* d_ws, size_t ws_size,
                              hipStream_t stream) {
    const float* X      = (const float*)d_in[0];
    const float* query  = (const float*)d_in[1];
    const int*   len    = (const int*)  d_in[2];
    const float* w      = (const float*)d_in[3];
    const float* u      = (const float*)d_in[4];
    const float* v      = (const float*)d_in[5];

    float* out     = (float*)d_out;
    float* score   = out;
    float* weights = out + (size_t)B * T;
    float* expec   = out + (size_t)2 * B * T;

    // ws layout: uq 64K | partialS 1M | WhF 512K | WlF 512K  (~2.1 MB)
    float* uq       = (float*)d_ws;
    float* partialS = uq + (size_t)B * D;                       // 262144 floats
    uint4* WhF      = (uint4*)(partialS + (size_t)4 * NROW);    // 32768 uint4
    uint4* WlF      = WhF + 32768;
    float* part     = partialS;   // alias: 16*B*D floats = 1MB, partialS dead by then

    k_uq         <<<B,            TPB, 0, stream>>>(query, u, uq);
    k_convW      <<<128,          TPB, 0, stream>>>(w, WhF, WlF);
    k_gemm       <<<2048,         TPB, 0, stream>>>(X, WhF, WlF, v, uq, partialS);
    k_csm        <<<B,            TPB, 0, stream>>>(partialS, len, score, weights);
    k_exp_partial<<<B * 16,       128, 0, stream>>>(X, weights, part);
    k_exp_reduce <<<B * D / TPB,  TPB, 0, stream>>>(part, expec);
}